// Round 7
// baseline (112.100 us; speedup 1.0000x reference)
//
#include <hip/hip_runtime.h>
#include <stdint.h>

#define LSEQ 256
#define EMB  256
#define K3F  768
#define SCOFF (4 * 256 * 256 * 6)

typedef short bf16x8 __attribute__((ext_vector_type(8)));
typedef float f32x4  __attribute__((ext_vector_type(4)));

__device__ __forceinline__ uint16_t f2bf(float x) {
    union { float f; uint32_t u; } c; c.f = x;
    uint32_t r = c.u + 0x7fffu + ((c.u >> 16) & 1u);
    return (uint16_t)(r >> 16);
}
__device__ __forceinline__ float bfhi(uint32_t u) {   // high half -> float
    union { uint32_t u; float f; } c; c.u = u & 0xffff0000u; return c.f;
}
__device__ __forceinline__ float bflo(uint32_t u) {   // low half -> float
    union { uint32_t u; float f; } c; c.u = u << 16; return c.f;
}

// ---------- prep: gather->embB bf16 (rows 4+l, zero halo), wprep->Wt[t][c][i] bf16
__global__ __launch_bounds__(256) void k_prep(const int* __restrict__ ids,
                                              const float* __restrict__ table,
                                              const float* __restrict__ w2,
                                              const float* __restrict__ w3,
                                              const float* __restrict__ w4,
                                              uint16_t* __restrict__ embB,
                                              uint16_t* __restrict__ Wt2,
                                              uint16_t* __restrict__ Wt3,
                                              uint16_t* __restrict__ Wt4) {
    int blk = blockIdx.x, tid = threadIdx.x;
    if (blk < 32) {                       // gather: 4b x 8 l-chunks of 32
        int b = blk >> 3, l0 = (blk & 7) << 5;
        int r = tid >> 3, p = tid & 7;
        int id = ids[(b << 8) + l0 + r];
        const float* src = table + (size_t)id * EMB + p * 32;
        uint16_t* dst = embB + (size_t)(b * 272 + 4 + l0 + r) * 256 + p * 32;
#pragma unroll
        for (int s = 0; s < 8; ++s) {
            float4 v = *(const float4*)(src + 4 * s);
            uint32_t lo = f2bf(v.x) | ((uint32_t)f2bf(v.y) << 16);
            uint32_t hi = f2bf(v.z) | ((uint32_t)f2bf(v.w) << 16);
            *(uint2*)(dst + 4 * s) = make_uint2(lo, hi);
        }
    } else if (blk < 36) {                // zero pad rows 0..3, 260..271
        int b = blk - 32;
        int ri = tid >> 4;
        int row = ri < 4 ? ri : 256 + ri;
        int off = (tid & 15) * 16;
        uint16_t* dst = embB + (size_t)(b * 272 + row) * 256 + off;
        *(uint4*)dst = make_uint4(0, 0, 0, 0);
        *(uint4*)(dst + 8) = make_uint4(0, 0, 0, 0);
    } else {                              // wprep: thread = (c,i)
        int n = (blk - 36) * 256 + tid;
        if (n < 65536) {
            int c = n >> 8, i = n & 255;
            float2 v = *(const float2*)(w2 + (c << 9) + (i << 1));
            Wt2[c * 256 + i]         = f2bf(v.x);
            Wt2[65536 + c * 256 + i] = f2bf(v.y);
        } else if (n < 131072) {
            int m = n - 65536;
            int c = m >> 8, i = m & 255;
            const float* s = w3 + c * 768 + i * 3;
#pragma unroll
            for (int t = 0; t < 3; ++t)
                Wt3[t * 65536 + c * 256 + i] = f2bf(s[t]);
        } else {
            int m = n - 131072;
            int c = m >> 8, i = m & 255;
            float4 v = *(const float4*)(w4 + (c << 10) + (i << 2));
            Wt4[c * 256 + i]              = f2bf(v.x);
            Wt4[65536 + c * 256 + i]      = f2bf(v.y);
            Wt4[2 * 65536 + c * 256 + i]  = f2bf(v.z);
            Wt4[3 * 65536 + c * 256 + i]  = f2bf(v.w);
        }
    }
}

// ---------- conv as MFMA GEMM, 32c x 32l tiles, i-chunk 64; epilogue: VB only
template <int K, int PAD>
__device__ __forceinline__ void convg_body(const uint16_t* __restrict__ Wt,
                                           const float* __restrict__ bias,
                                           const uint16_t* __restrict__ embB,
                                           uint16_t* __restrict__ VB,
                                           int b, int c0, int l0, int gbase,
                                           uint16_t (*As)[32][72], uint16_t (*Bs)[72],
                                           float* bs) {
    const int tid = threadIdx.x;
    if (tid < 32) bs[tid] = bias[c0 + tid];
    const int lane = tid & 63, wave = tid >> 6;
    const int ms = wave >> 1, ns = wave & 1;
    const int m = lane & 15, q = lane >> 4;
    const int ar = tid >> 3, aseg = (tid & 7) * 8;

    f32x4 acc;
#pragma unroll
    for (int z = 0; z < 4; ++z) acc[z] = 0.f;

    for (int i0 = 0; i0 < EMB; i0 += 64) {
        __syncthreads();
#pragma unroll
        for (int t = 0; t < K; ++t) {
            const uint16_t* src = Wt + (size_t)((t * 256 + c0 + ar) * 256 + i0) + aseg;
            *(bf16x8*)&As[t][ar][aseg] = *(const bf16x8*)src;
        }
        {   // B rows: embB rows 3+l0 .. 3+l0+35 (36 rows x 64 i)
            const uint16_t* src = embB + (size_t)(b * 272 + 3 + l0 + ar) * 256 + i0 + aseg;
            *(bf16x8*)&Bs[ar][aseg] = *(const bf16x8*)src;
            if (tid < 32) {
                int r2 = 32 + (tid >> 3);
                const uint16_t* s2 = embB + (size_t)(b * 272 + 3 + l0 + r2) * 256 + i0 + aseg;
                *(bf16x8*)&Bs[r2][aseg] = *(const bf16x8*)s2;
            }
        }
        __syncthreads();
#pragma unroll
        for (int t = 0; t < K; ++t) {
#pragma unroll
            for (int kh = 0; kh < 64; kh += 32) {
                bf16x8 afr = *(const bf16x8*)&As[t][ms * 16 + m][kh + q * 8];
                bf16x8 bfr = *(const bf16x8*)&Bs[ns * 16 + m + t - PAD + 1][kh + q * 8];
                acc = __builtin_amdgcn_mfma_f32_16x16x32_bf16(afr, bfr, acc, 0, 0, 0);
            }
        }
    }
    __syncthreads();
    float (*Cs)[36] = (float(*)[36])As;   // reuse As
#pragma unroll
    for (int rg = 0; rg < 4; ++rg)
        Cs[ms * 16 + q * 4 + rg][ns * 16 + m] = acc[rg];
    __syncthreads();
    const int l = tid >> 3, cs = (tid & 7) * 4;
    union { uint16_t h[4]; uint32_t d[2]; } pk;
#pragma unroll
    for (int v = 0; v < 4; ++v) pk.h[v] = f2bf(Cs[cs + v][l] + bs[cs + v]);
    uint16_t* vdst = VB + (size_t)(b * 256 + l0 + l) * K3F + gbase + c0 + cs;
    *(uint2*)vdst = *(const uint2*)pk.d;
}

__global__ __launch_bounds__(256, 2) void k_convg(const uint16_t* __restrict__ Wt2,
                                                  const uint16_t* __restrict__ Wt3,
                                                  const uint16_t* __restrict__ Wt4,
                                                  const float* __restrict__ b2,
                                                  const float* __restrict__ b3,
                                                  const float* __restrict__ b4,
                                                  const uint16_t* __restrict__ embB,
                                                  uint16_t* __restrict__ VB) {
    __shared__ uint16_t As[4][32][72];
    __shared__ uint16_t Bs[36][72];
    __shared__ float bs[32];
    int blk = blockIdx.x;                 // 768 = 4b * 3g * 8c0 * 8l0
    int b = blk & 3, rest = blk >> 2;
    int g = rest >> 6, rr = rest & 63;
    int c0 = (rr >> 3) * 32, l0 = (rr & 7) * 32;
    if (g == 0)      convg_body<2, 0>(Wt2, b2, embB, VB, b, c0, l0, 0,   As, Bs, bs);
    else if (g == 1) convg_body<3, 1>(Wt3, b3, embB, VB, b, c0, l0, 256, As, Bs, bs);
    else             convg_body<4, 1>(Wt4, b4, embB, VB, b, c0, l0, 512, As, Bs, bs);
}

// ---------- pair GEMM: block = (b, c, i-tile 32, j-pair 64): 896 blocks.
// A-tile = VB i-rows scaled by tw_c[k] in-register (U never materialized).
__global__ __launch_bounds__(256, 4) void k_pairc3(const uint16_t* __restrict__ VB,
                                                   const float* __restrict__ tw,
                                                   const float* __restrict__ sw,
                                                   const float* __restrict__ tb,
                                                   const float* __restrict__ sb,
                                                   float* __restrict__ dout) {
    __shared__ uint16_t T[96][136];       // rows 0..31 = scaled A(i), 32..95 = VB(j)
    int blk = blockIdx.x;
    int b = blk & 3, it = (blk >> 2) & 7;
    int rest = blk >> 5;
    int c = rest % 7, jp = rest / 7;
    int i0 = it * 32, j0 = jp * 64;
    int tid = threadIdx.x;
    int lane = tid & 63, wave = tid >> 6;
    int iw = wave >> 1, jw = wave & 1;
    int m = lane & 15, q = lane >> 4;

    const float* twp = (c < 6) ? tw + c * K3F : sw;
    const int ra = tid >> 3, sa = (tid & 7) * 16;   // A: 32 rows x 8 thr x 16 halfs
    const int rb = tid >> 2, sb2 = (tid & 3) * 32;  // B: 64 rows x 4 thr x 32 halfs
    const uint16_t* srcA = VB + (size_t)(b * 256 + i0 + ra) * K3F + sa;
    const uint16_t* srcB = VB + (size_t)(b * 256 + j0 + rb) * K3F + sb2;

    f32x4 acc[2];
#pragma unroll
    for (int n = 0; n < 2; ++n)
#pragma unroll
        for (int z = 0; z < 4; ++z) acc[n][z] = 0.f;

    for (int kc = 0; kc < K3F; kc += 128) {
        __syncthreads();
        {   // A staging: load 16 halfs, scale by tw fragment, repack
            uint4 a0 = *(const uint4*)(srcA + kc);
            uint4 a1 = *(const uint4*)(srcA + kc + 8);
            const float* tp = twp + kc + sa;
            float4 t0 = *(const float4*)tp, t1 = *(const float4*)(tp + 4);
            float4 t2 = *(const float4*)(tp + 8), t3 = *(const float4*)(tp + 12);
            uint32_t o[8];
            o[0] = f2bf(bflo(a0.x) * t0.x) | ((uint32_t)f2bf(bfhi(a0.x) * t0.y) << 16);
            o[1] = f2bf(bflo(a0.y) * t0.z) | ((uint32_t)f2bf(bfhi(a0.y) * t0.w) << 16);
            o[2] = f2bf(bflo(a0.z) * t1.x) | ((uint32_t)f2bf(bfhi(a0.z) * t1.y) << 16);
            o[3] = f2bf(bflo(a0.w) * t1.z) | ((uint32_t)f2bf(bfhi(a0.w) * t1.w) << 16);
            o[4] = f2bf(bflo(a1.x) * t2.x) | ((uint32_t)f2bf(bfhi(a1.x) * t2.y) << 16);
            o[5] = f2bf(bflo(a1.y) * t2.z) | ((uint32_t)f2bf(bfhi(a1.y) * t2.w) << 16);
            o[6] = f2bf(bflo(a1.z) * t3.x) | ((uint32_t)f2bf(bfhi(a1.z) * t3.y) << 16);
            o[7] = f2bf(bflo(a1.w) * t3.z) | ((uint32_t)f2bf(bfhi(a1.w) * t3.w) << 16);
            *(uint4*)&T[ra][sa]     = make_uint4(o[0], o[1], o[2], o[3]);
            *(uint4*)&T[ra][sa + 8] = make_uint4(o[4], o[5], o[6], o[7]);
        }
        {   // B staging: raw copy, 32 halfs
            const uint16_t* s = srcB + kc;
            *(bf16x8*)&T[32 + rb][sb2]      = *(const bf16x8*)s;
            *(bf16x8*)&T[32 + rb][sb2 + 8]  = *(const bf16x8*)(s + 8);
            *(bf16x8*)&T[32 + rb][sb2 + 16] = *(const bf16x8*)(s + 16);
            *(bf16x8*)&T[32 + rb][sb2 + 24] = *(const bf16x8*)(s + 24);
        }
        __syncthreads();
#pragma unroll
        for (int kh = 0; kh < 4; ++kh) {
            bf16x8 afr  = *(const bf16x8*)&T[iw * 16 + m][kh * 32 + q * 8];
            bf16x8 bfr0 = *(const bf16x8*)&T[32 + jw * 32 + m][kh * 32 + q * 8];
            bf16x8 bfr1 = *(const bf16x8*)&T[32 + jw * 32 + 16 + m][kh * 32 + q * 8];
            acc[0] = __builtin_amdgcn_mfma_f32_16x16x32_bf16(afr, bfr0, acc[0], 0, 0, 0);
            acc[1] = __builtin_amdgcn_mfma_f32_16x16x32_bf16(afr, bfr1, acc[1], 0, 0, 0);
        }
    }
    float bias = (c < 6) ? tb[c] : sb[0];
#pragma unroll
    for (int n = 0; n < 2; ++n)
#pragma unroll
        for (int rg = 0; rg < 4; ++rg) {
            int i = i0 + iw * 16 + q * 4 + rg;
            int j = j0 + jw * 32 + n * 16 + m;
            float v = acc[n][rg] + bias;
            if (c < 6) dout[((size_t)(b * 256 + i) * 256 + j) * 6 + c] = v;
            else       dout[SCOFF + (size_t)(b * 256 + i) * 256 + j] = v;
        }
}

extern "C" void kernel_launch(void* const* d_in, const int* in_sizes, int n_in,
                              void* d_out, int out_size, void* d_ws, size_t ws_size,
                              hipStream_t stream) {
    const int*   ids   = (const int*)d_in[0];
    const float* table = (const float*)d_in[1];
    const float* w2 = (const float*)d_in[2];
    const float* b2 = (const float*)d_in[3];
    const float* w3 = (const float*)d_in[4];
    const float* b3 = (const float*)d_in[5];
    const float* w4 = (const float*)d_in[6];
    const float* b4 = (const float*)d_in[7];
    const float* tw = (const float*)d_in[8];
    const float* tb = (const float*)d_in[9];
    const float* sw = (const float*)d_in[10];
    const float* sb = (const float*)d_in[11];
    float* dout = (float*)d_out;

    uint8_t* wsb = (uint8_t*)d_ws;
    uint16_t* VB   = (uint16_t*)(wsb + 0);           //  1,572,864 B
    uint16_t* embB = (uint16_t*)(wsb + 1572864);     //    557,056 B
    uint16_t* Wt2  = (uint16_t*)(wsb + 2129920);     //    262,144 B
    uint16_t* Wt3  = (uint16_t*)(wsb + 2392064);     //    393,216 B
    uint16_t* Wt4  = (uint16_t*)(wsb + 2785280);     //    524,288 B -> 3,309,568 total

    hipLaunchKernelGGL(k_prep,   dim3(804), dim3(256), 0, stream,
                       ids, table, w2, w3, w4, embB, Wt2, Wt3, Wt4);
    hipLaunchKernelGGL(k_convg,  dim3(768), dim3(256), 0, stream,
                       Wt2, Wt3, Wt4, b2, b3, b4, embB, VB);
    hipLaunchKernelGGL(k_pairc3, dim3(896), dim3(256), 0, stream,
                       VB, tw, sw, tb, sb, dout);
}

// Round 8
// 109.431 us; speedup vs baseline: 1.0244x; 1.0244x over previous
//
#include <hip/hip_runtime.h>
#include <stdint.h>

#define LSEQ 256
#define EMB  256
#define K3F  768
#define SCOFF (4 * 256 * 256 * 6)

typedef short bf16x8 __attribute__((ext_vector_type(8)));
typedef float f32x4  __attribute__((ext_vector_type(4)));

__device__ __forceinline__ uint16_t f2bf(float x) {
    union { float f; uint32_t u; } c; c.f = x;
    uint32_t r = c.u + 0x7fffu + ((c.u >> 16) & 1u);
    return (uint16_t)(r >> 16);
}

// ---------- prep: gather->embB bf16 (rows 4+l, zero halo), wprep->Wt[t][c][i] bf16
// grid 804 = 32 gather + 4 pad + 768 wprep (one thread per (c,i), K loads/stores)
__global__ __launch_bounds__(256) void k_prep(const int* __restrict__ ids,
                                              const float* __restrict__ table,
                                              const float* __restrict__ w2,
                                              const float* __restrict__ w3,
                                              const float* __restrict__ w4,
                                              uint16_t* __restrict__ embB,
                                              uint16_t* __restrict__ Wt2,
                                              uint16_t* __restrict__ Wt3,
                                              uint16_t* __restrict__ Wt4) {
    int blk = blockIdx.x, tid = threadIdx.x;
    if (blk < 32) {                       // gather: 4b x 8 l-chunks of 32
        int b = blk >> 3, l0 = (blk & 7) << 5;
        int r = tid >> 3, p = tid & 7;
        int id = ids[(b << 8) + l0 + r];
        const float* src = table + (size_t)id * EMB + p * 32;
        uint16_t* dst = embB + (size_t)(b * 272 + 4 + l0 + r) * 256 + p * 32;
#pragma unroll
        for (int s = 0; s < 8; ++s) {
            float4 v = *(const float4*)(src + 4 * s);
            uint32_t lo = f2bf(v.x) | ((uint32_t)f2bf(v.y) << 16);
            uint32_t hi = f2bf(v.z) | ((uint32_t)f2bf(v.w) << 16);
            *(uint2*)(dst + 4 * s) = make_uint2(lo, hi);
        }
    } else if (blk < 36) {                // zero pad rows 0..3, 260..271
        int b = blk - 32;
        int ri = tid >> 4;
        int row = ri < 4 ? ri : 256 + ri;
        int off = (tid & 15) * 16;
        uint16_t* dst = embB + (size_t)(b * 272 + row) * 256 + off;
        *(uint4*)dst = make_uint4(0, 0, 0, 0);
        *(uint4*)(dst + 8) = make_uint4(0, 0, 0, 0);
    } else {                              // wprep: thread = (c,i), 65536 per group
        int n = (blk - 36) * 256 + tid;
        if (n < 65536) {
            int c = n >> 8, i = n & 255;
            float2 v = *(const float2*)(w2 + (c << 9) + (i << 1));
            Wt2[c * 256 + i]         = f2bf(v.x);
            Wt2[65536 + c * 256 + i] = f2bf(v.y);
        } else if (n < 131072) {
            int m = n - 65536;
            int c = m >> 8, i = m & 255;
            const float* s = w3 + c * 768 + i * 3;
#pragma unroll
            for (int t = 0; t < 3; ++t)
                Wt3[t * 65536 + c * 256 + i] = f2bf(s[t]);
        } else {
            int m = n - 131072;
            int c = m >> 8, i = m & 255;
            float4 v = *(const float4*)(w4 + (c << 10) + (i << 2));
            Wt4[c * 256 + i]              = f2bf(v.x);
            Wt4[65536 + c * 256 + i]      = f2bf(v.y);
            Wt4[2 * 65536 + c * 256 + i]  = f2bf(v.z);
            Wt4[3 * 65536 + c * 256 + i]  = f2bf(v.w);
        }
    }
}

// ---------- conv as MFMA GEMM, 32c x 32l tiles, i-chunk 64 (R4/R6 proven form)
template <int K, int PAD>
__device__ __forceinline__ void convg_body(const uint16_t* __restrict__ Wt,
                                           const float* __restrict__ bias,
                                           const uint16_t* __restrict__ embB,
                                           const float* __restrict__ tw,
                                           const float* __restrict__ sw,
                                           uint16_t* __restrict__ VB,
                                           uint16_t* __restrict__ U,
                                           int b, int c0, int l0, int gbase,
                                           uint16_t (*As)[32][72], uint16_t (*Bs)[72],
                                           float (*twb)[32]) {
    const int tid = threadIdx.x;
    {   // stage tw rows (7) + bias into twb[8][32]
        int cm = tid >> 5, cc = tid & 31;
        int gch = gbase + c0 + cc;
        float v;
        if (cm < 6) v = tw[cm * K3F + gch];
        else if (cm == 6) v = sw[gch];
        else v = bias[c0 + cc];
        twb[cm][cc] = v;
    }
    const int lane = tid & 63, wave = tid >> 6;
    const int ms = wave >> 1, ns = wave & 1;
    const int m = lane & 15, q = lane >> 4;
    const int ar = tid >> 3, aseg = (tid & 7) * 8;

    f32x4 acc;
#pragma unroll
    for (int z = 0; z < 4; ++z) acc[z] = 0.f;

    for (int i0 = 0; i0 < EMB; i0 += 64) {
        __syncthreads();
#pragma unroll
        for (int t = 0; t < K; ++t) {
            const uint16_t* src = Wt + (size_t)((t * 256 + c0 + ar) * 256 + i0) + aseg;
            *(bf16x8*)&As[t][ar][aseg] = *(const bf16x8*)src;
        }
        {   // B rows: embB rows 3+l0 .. 3+l0+35 (36 rows x 64 i)
            const uint16_t* src = embB + (size_t)(b * 272 + 3 + l0 + ar) * 256 + i0 + aseg;
            *(bf16x8*)&Bs[ar][aseg] = *(const bf16x8*)src;
            if (tid < 32) {
                int r2 = 32 + (tid >> 3);
                const uint16_t* s2 = embB + (size_t)(b * 272 + 3 + l0 + r2) * 256 + i0 + aseg;
                *(bf16x8*)&Bs[r2][aseg] = *(const bf16x8*)s2;
            }
        }
        __syncthreads();
#pragma unroll
        for (int t = 0; t < K; ++t) {
#pragma unroll
            for (int kh = 0; kh < 64; kh += 32) {
                bf16x8 afr = *(const bf16x8*)&As[t][ms * 16 + m][kh + q * 8];
                bf16x8 bfr = *(const bf16x8*)&Bs[ns * 16 + m + t - PAD + 1][kh + q * 8];
                acc = __builtin_amdgcn_mfma_f32_16x16x32_bf16(afr, bfr, acc, 0, 0, 0);
            }
        }
    }
    __syncthreads();
    float (*Cs)[36] = (float(*)[36])As;   // 4,608 B reuse
#pragma unroll
    for (int rg = 0; rg < 4; ++rg)
        Cs[ms * 16 + q * 4 + rg][ns * 16 + m] = acc[rg];
    __syncthreads();
    const int l = tid >> 3, cs = (tid & 7) * 4;
    float vals[4];
#pragma unroll
    for (int v = 0; v < 4; ++v) vals[v] = Cs[cs + v][l] + twb[7][cs + v];
    union { uint16_t h[4]; uint32_t d[2]; } pk;
#pragma unroll
    for (int v = 0; v < 4; ++v) pk.h[v] = f2bf(vals[v]);
    uint16_t* vdst = VB + (size_t)(b * 256 + l0 + l) * K3F + gbase + c0 + cs;
    *(uint2*)vdst = *(const uint2*)pk.d;
#pragma unroll
    for (int cm = 0; cm < 7; ++cm) {
#pragma unroll
        for (int v = 0; v < 4; ++v) pk.h[v] = f2bf(vals[v] * twb[cm][cs + v]);
        uint16_t* udst = U + (size_t)((b * 7 + cm) * 256 + l0 + l) * K3F + gbase + c0 + cs;
        *(uint2*)udst = *(const uint2*)pk.d;
    }
}

__global__ __launch_bounds__(256, 2) void k_convg(const uint16_t* __restrict__ Wt2,
                                                  const uint16_t* __restrict__ Wt3,
                                                  const uint16_t* __restrict__ Wt4,
                                                  const float* __restrict__ b2,
                                                  const float* __restrict__ b3,
                                                  const float* __restrict__ b4,
                                                  const uint16_t* __restrict__ embB,
                                                  const float* __restrict__ tw,
                                                  const float* __restrict__ sw,
                                                  uint16_t* __restrict__ VB,
                                                  uint16_t* __restrict__ U) {
    __shared__ uint16_t As[4][32][72];
    __shared__ uint16_t Bs[36][72];
    __shared__ float twb[8][32];
    int blk = blockIdx.x;                 // 768 = 4b * 3g * 8c0 * 8l0
    int b = blk & 3, rest = blk >> 2;
    int g = rest >> 6, rr = rest & 63;
    int c0 = (rr >> 3) * 32, l0 = (rr & 7) * 32;
    if (g == 0)      convg_body<2, 0>(Wt2, b2, embB, tw, sw, VB, U, b, c0, l0, 0,   As, Bs, twb);
    else if (g == 1) convg_body<3, 1>(Wt3, b3, embB, tw, sw, VB, U, b, c0, l0, 256, As, Bs, twb);
    else             convg_body<4, 1>(Wt4, b4, embB, tw, sw, VB, U, b, c0, l0, 512, As, Bs, twb);
}

// ---------- pair GEMM: block = (b, c, i-tile 32, j-pair 64): 896 blocks
// same-(b,c,it) blocks are 224 apart (224 % 8 == 0 -> same XCD, U rows L2-hot)
__global__ __launch_bounds__(256, 4) void k_pairc2(const uint16_t* __restrict__ U,
                                                   const uint16_t* __restrict__ VB,
                                                   const float* __restrict__ tb,
                                                   const float* __restrict__ sb,
                                                   float* __restrict__ dout) {
    __shared__ uint16_t T[96][136];       // rows 0..31 = U(i), 32..95 = VB(j0..j0+63)
    int blk = blockIdx.x;
    int b = blk & 3, it = (blk >> 2) & 7;
    int rest = blk >> 5;
    int c = rest % 7, jp = rest / 7;
    int i0 = it * 32, j0 = jp * 64;
    int tid = threadIdx.x;
    int lane = tid & 63, wave = tid >> 6;
    int iw = wave >> 1, jw = wave & 1;
    int m = lane & 15, q = lane >> 4;
    int rr = tid >> 3, seg = (tid & 7) * 16;   // 32 rows/pass, 8 thr/row, 16 halfs

    const uint16_t* srcp[3];
    srcp[0] = U + (size_t)((b * 7 + c) * 256 + i0 + rr) * K3F + seg;
    srcp[1] = VB + (size_t)(b * 256 + j0 + rr) * K3F + seg;
    srcp[2] = VB + (size_t)(b * 256 + j0 + 32 + rr) * K3F + seg;

    f32x4 acc[2];
#pragma unroll
    for (int n = 0; n < 2; ++n)
#pragma unroll
        for (int z = 0; z < 4; ++z) acc[n][z] = 0.f;

    for (int kc = 0; kc < K3F; kc += 128) {
        __syncthreads();
#pragma unroll
        for (int p = 0; p < 3; ++p) {
            const uint16_t* s = srcp[p] + kc;
            *(bf16x8*)&T[p * 32 + rr][seg]     = *(const bf16x8*)s;
            *(bf16x8*)&T[p * 32 + rr][seg + 8] = *(const bf16x8*)(s + 8);
        }
        __syncthreads();
#pragma unroll
        for (int kh = 0; kh < 4; ++kh) {
            bf16x8 afr  = *(const bf16x8*)&T[iw * 16 + m][kh * 32 + q * 8];
            bf16x8 bfr0 = *(const bf16x8*)&T[32 + jw * 32 + m][kh * 32 + q * 8];
            bf16x8 bfr1 = *(const bf16x8*)&T[32 + jw * 32 + 16 + m][kh * 32 + q * 8];
            acc[0] = __builtin_amdgcn_mfma_f32_16x16x32_bf16(afr, bfr0, acc[0], 0, 0, 0);
            acc[1] = __builtin_amdgcn_mfma_f32_16x16x32_bf16(afr, bfr1, acc[1], 0, 0, 0);
        }
    }
    float bias = (c < 6) ? tb[c] : sb[0];
#pragma unroll
    for (int n = 0; n < 2; ++n)
#pragma unroll
        for (int rg = 0; rg < 4; ++rg) {
            int i = i0 + iw * 16 + q * 4 + rg;
            int j = j0 + jw * 32 + n * 16 + m;
            float v = acc[n][rg] + bias;
            if (c < 6) dout[((size_t)(b * 256 + i) * 256 + j) * 6 + c] = v;
            else       dout[SCOFF + (size_t)(b * 256 + i) * 256 + j] = v;
        }
}

extern "C" void kernel_launch(void* const* d_in, const int* in_sizes, int n_in,
                              void* d_out, int out_size, void* d_ws, size_t ws_size,
                              hipStream_t stream) {
    const int*   ids   = (const int*)d_in[0];
    const float* table = (const float*)d_in[1];
    const float* w2 = (const float*)d_in[2];
    const float* b2 = (const float*)d_in[3];
    const float* w3 = (const float*)d_in[4];
    const float* b3 = (const float*)d_in[5];
    const float* w4 = (const float*)d_in[6];
    const float* b4 = (const float*)d_in[7];
    const float* tw = (const float*)d_in[8];
    const float* tb = (const float*)d_in[9];
    const float* sw = (const float*)d_in[10];
    const float* sb = (const float*)d_in[11];
    float* dout = (float*)d_out;

    uint8_t* wsb = (uint8_t*)d_ws;
    uint16_t* VB   = (uint16_t*)(wsb + 0);           //  1,572,864 B
    uint16_t* U    = (uint16_t*)(wsb + 1572864);     // 11,010,048 B
    uint16_t* embB = (uint16_t*)(wsb + 12582912);    //    557,056 B
    uint16_t* Wt2  = (uint16_t*)(wsb + 13139968);    //    262,144 B
    uint16_t* Wt3  = (uint16_t*)(wsb + 13402112);    //    393,216 B
    uint16_t* Wt4  = (uint16_t*)(wsb + 13795328);    //    524,288 B -> 14,319,616 total

    hipLaunchKernelGGL(k_prep,   dim3(804), dim3(256), 0, stream,
                       ids, table, w2, w3, w4, embB, Wt2, Wt3, Wt4);
    hipLaunchKernelGGL(k_convg,  dim3(768), dim3(256), 0, stream,
                       Wt2, Wt3, Wt4, b2, b3, b4, embB, tw, sw, VB, U);
    hipLaunchKernelGGL(k_pairc2, dim3(896), dim3(256), 0, stream, U, VB, tb, sb, dout);
}